// Round 3
// baseline (1428.575 us; speedup 1.0000x reference)
//
#include <hip/hip_runtime.h>

// Layer3bitWithZero: out = A @ (q * s + z), groupwise dequant (GROUPSIZE=64)
// Wire dtypes (fp16 canonicalized to f32 by harness):
//   A: (2048, 4096) float32 ; q: (4096, 11264) int32 in [0,8)
//   s, z: (64, 11264) float32 ; out: (2048, 11264) float32
// Compute: fp16 MFMA (A is fp16-valued -> f32->fp16 conversion exact).

#define M_DIM 2048
#define N_DIM 11264
#define K_DIM 4096

constexpr int BM = 128, BN = 128, BK = 64;
constexpr int GRID_M = M_DIM / BM;       // 16
constexpr int GRID_N = N_DIM / BN;       // 88
constexpr int NBLK = GRID_M * GRID_N;    // 1408 = 8 * 176
constexpr int KTILES = K_DIM / BK;       // 64

typedef __attribute__((ext_vector_type(8))) _Float16 half8;
typedef __attribute__((ext_vector_type(4))) float floatx4;

__global__ void __launch_bounds__(256)
l3z_gemm(const float* __restrict__ A, const int* __restrict__ Q,
         const float* __restrict__ S, const float* __restrict__ Z,
         float* __restrict__ out)
{
    // A tile: strip-major [m][ks'] where ks' = ks ^ (m&7)  (8 strips of 8 fp16 per row)
    // B tile: strip-major [ks][n] (dequantized fp16)
    __shared__ _Float16 ldsA[BM * BK];   // 16 KiB
    __shared__ _Float16 ldsB[BK * BN];   // 16 KiB

    // XCD-bijective swizzle (NBLK = 1408 divisible by 8): bm fastest within an XCD
    int bid = blockIdx.x;
    int vid = (bid & 7) * (NBLK / 8) + (bid >> 3);
    int bm = vid % GRID_M;
    int bn = vid / GRID_M;
    int m0 = bm * BM, n0 = bn * BN;

    int tid  = threadIdx.x;
    int lane = tid & 63;
    int wv   = tid >> 6;
    int wr   = (wv >> 1) * 64;   // wave row quadrant
    int wc   = (wv & 1) * 64;    // wave col quadrant

    // B staging coords: thread -> fixed column n, k-strip base 0 or 8
    int nB  = tid & 127;
    int kb0 = (tid >> 7) * 8;
    const int* qcol = Q + n0 + nB;

    floatx4 acc[4][4];
#pragma unroll
    for (int i = 0; i < 4; ++i)
#pragma unroll
        for (int j = 0; j < 4; ++j)
            acc[i][j] = (floatx4){0.f, 0.f, 0.f, 0.f};

    // ---------------- staging ----------------
    auto stage = [&](int t) {
        int k0 = t * BK;
        // A: each thread moves 4 strips of 8 f32 -> 8 fp16.  m = slot>>3, ks = tid&7
#pragma unroll
        for (int i = 0; i < 4; ++i) {
            int slot = i * 256 + tid;
            int m  = slot >> 3;
            int ks = tid & 7;
            const float* src = A + (size_t)(m0 + m) * K_DIM + (k0 + ks * 8);
            float4 f0 = *(const float4*)(src);
            float4 f1 = *(const float4*)(src + 4);
            half8 h;
            h[0] = (_Float16)f0.x; h[1] = (_Float16)f0.y;
            h[2] = (_Float16)f0.z; h[3] = (_Float16)f0.w;
            h[4] = (_Float16)f1.x; h[5] = (_Float16)f1.y;
            h[6] = (_Float16)f1.z; h[7] = (_Float16)f1.w;
            int ksx = ks ^ (m & 7);                       // XOR swizzle (write side)
            *(half8*)(ldsA + (size_t)((m << 3) + ksx) * 8) = h;
        }
        // B: dequant q -> fp16 strips. Group index == t since BK == GROUPSIZE.
        float sf = S[(size_t)t * N_DIM + n0 + nB];
        float zf = Z[(size_t)t * N_DIM + n0 + nB];
#pragma unroll
        for (int i = 0; i < 4; ++i) {
            int kb = kb0 + i * 16;
            half8 w;
#pragma unroll
            for (int j = 0; j < 8; ++j) {
                int v = qcol[(size_t)(k0 + kb + j) * N_DIM];
                w[j] = (_Float16)fmaf((float)v, sf, zf);
            }
            int ks = kb >> 3;
            *(half8*)(ldsB + (size_t)(ks * 128 + nB) * 8) = w;
        }
    };

    // ---------------- main loop ----------------
    stage(0);
    __syncthreads();

    for (int t = 0; t < KTILES; ++t) {
#pragma unroll
        for (int half = 0; half < 2; ++half) {
            int ksb = half * 4 + (lane >> 4);   // this lane-group's k-strip
            half8 af[4], bfr[4];
#pragma unroll
            for (int mf = 0; mf < 4; ++mf) {
                int r = wr + mf * 16 + (lane & 15);
                int ksx = ksb ^ (r & 7);                  // XOR swizzle (read side)
                af[mf] = *(const half8*)(ldsA + (size_t)((r << 3) + ksx) * 8);
            }
#pragma unroll
            for (int nf = 0; nf < 4; ++nf) {
                int c = wc + nf * 16 + (lane & 15);
                bfr[nf] = *(const half8*)(ldsB + (size_t)(ksb * 128 + c) * 8);
            }
#pragma unroll
            for (int mf = 0; mf < 4; ++mf)
#pragma unroll
                for (int nf = 0; nf < 4; ++nf)
                    acc[mf][nf] = __builtin_amdgcn_mfma_f32_16x16x32_f16(
                        af[mf], bfr[nf], acc[mf][nf], 0, 0, 0);
        }

        if (t + 1 < KTILES) {
            __syncthreads();       // all waves done reading this tile
            stage(t + 1);
            __syncthreads();       // staging drained before next compute
        }
    }

    // ---------------- epilogue ----------------
    // C/D layout (dtype-independent, verified m89/m91): col = lane&15, row = (lane>>4)*4 + reg
    int rbase = m0 + wr + ((lane >> 4) << 2);
    int cbase = n0 + wc + (lane & 15);
#pragma unroll
    for (int mf = 0; mf < 4; ++mf)
#pragma unroll
        for (int nf = 0; nf < 4; ++nf)
#pragma unroll
            for (int rr = 0; rr < 4; ++rr) {
                int row = rbase + mf * 16 + rr;
                int col = cbase + nf * 16;
                out[(size_t)row * N_DIM + col] = acc[mf][nf][rr];
            }
}

extern "C" void kernel_launch(void* const* d_in, const int* in_sizes, int n_in,
                              void* d_out, int out_size, void* d_ws, size_t ws_size,
                              hipStream_t stream) {
    const float* A = (const float*)d_in[0];
    const int*   Q = (const int*)d_in[1];
    const float* S = (const float*)d_in[2];
    const float* Z = (const float*)d_in[3];
    float* O = (float*)d_out;

    l3z_gemm<<<dim3(NBLK), dim3(256), 0, stream>>>(A, Q, S, Z, O);
}

// Round 7
// 674.354 us; speedup vs baseline: 2.1184x; 2.1184x over previous
//
#include <hip/hip_runtime.h>

// Layer3bitWithZero: out = A @ (q * s + z), groupwise dequant (GROUPSIZE=64)
// Wire dtypes (fp16 canonicalized to f32 by harness):
//   A: (2048, 4096) float32 ; q: (4096, 11264) int32 in [0,8)
//   s, z: (64, 11264) float32 ; out: (2048, 11264) float32
// Compute: fp16 MFMA. Double-buffered LDS + async-STAGE split (issue loads
// early into regs, dequant+ds_write after compute, 1 barrier/tile).
// Round 7: resubmit of round 6 (container infra failure, never ran).

#define M_DIM 2048
#define N_DIM 11264
#define K_DIM 4096

constexpr int BM = 128, BN = 128, BK = 64;
constexpr int GRID_M = M_DIM / BM;       // 16
constexpr int GRID_N = N_DIM / BN;       // 88
constexpr int NBLK = GRID_M * GRID_N;    // 1408 = 8 * 176
constexpr int KTILES = K_DIM / BK;       // 64

typedef __attribute__((ext_vector_type(8))) _Float16 half8;
typedef __attribute__((ext_vector_type(2))) _Float16 half2v;
typedef __attribute__((ext_vector_type(4))) float floatx4;

static __device__ __forceinline__ half2v pkrtz(float a, float b) {
    return __builtin_bit_cast(half2v, __builtin_amdgcn_cvt_pkrtz(a, b));
}

__global__ void __launch_bounds__(256, 2)
l3z_gemm(const float* __restrict__ A, const int* __restrict__ Q,
         const float* __restrict__ S, const float* __restrict__ Z,
         float* __restrict__ out)
{
    // A tile: strip-major [m][ks'] , ks' = ks ^ (m&7)  (XOR swizzle, 8x8-fp16 strips)
    // B tile: strip-major [ks][n]
    __shared__ _Float16 ldsA[2][BM * BK];   // 2 x 16 KiB
    __shared__ _Float16 ldsB[2][BK * BN];   // 2 x 16 KiB

    // XCD-bijective swizzle (NBLK = 1408 = 8*176): bm fastest within an XCD
    int bid = blockIdx.x;
    int vid = (bid & 7) * (NBLK / 8) + (bid >> 3);
    int bm = vid % GRID_M;
    int bn = vid / GRID_M;
    int m0 = bm * BM, n0 = bn * BN;

    int tid  = threadIdx.x;
    int lane = tid & 63;
    int wv   = tid >> 6;
    int wr   = (wv >> 1) * 64;   // wave row quadrant
    int wc   = (wv & 1) * 64;    // wave col quadrant

    // B staging coords: thread -> fixed column n, k-strip base 0 or 8
    int nB  = tid & 127;
    int kb0 = (tid >> 7) * 8;
    const int* qcol = Q + n0 + nB;

    floatx4 acc[4][4];
#pragma unroll
    for (int i = 0; i < 4; ++i)
#pragma unroll
        for (int j = 0; j < 4; ++j)
            acc[i][j] = (floatx4){0.f, 0.f, 0.f, 0.f};

    // ---- prefetch registers (held across compute) ----
    float4 apre[4][2];     // 4 strips x 8 f32
    int    bpre[4][8];     // 32 q values
    float  spre, zpre;

    // Issue global loads for tile t (no waits here).
    auto issue = [&](int t) {
        int k0 = t * BK;
#pragma unroll
        for (int i = 0; i < 4; ++i) {
            int slot = i * 256 + tid;
            int m  = slot >> 3;
            int ks = tid & 7;
            const float* src = A + (size_t)(m0 + m) * K_DIM + (k0 + ks * 8);
            apre[i][0] = *(const float4*)(src);
            apre[i][1] = *(const float4*)(src + 4);
        }
        spre = S[(size_t)t * N_DIM + n0 + nB];
        zpre = Z[(size_t)t * N_DIM + n0 + nB];
#pragma unroll
        for (int i = 0; i < 4; ++i) {
            int kb = kb0 + i * 16;
#pragma unroll
            for (int j = 0; j < 8; ++j)
                bpre[i][j] = qcol[(size_t)(k0 + kb + j) * N_DIM];
        }
    };

    // Convert/dequant prefetched regs and write to LDS buffer `buf`.
    auto writeLds = [&](int buf) {
#pragma unroll
        for (int i = 0; i < 4; ++i) {
            int slot = i * 256 + tid;
            int m  = slot >> 3;
            int ks = tid & 7;
            // A values are fp16-representable -> RTZ pack is exact.
            half2v p0 = pkrtz(apre[i][0].x, apre[i][0].y);
            half2v p1 = pkrtz(apre[i][0].z, apre[i][0].w);
            half2v p2 = pkrtz(apre[i][1].x, apre[i][1].y);
            half2v p3 = pkrtz(apre[i][1].z, apre[i][1].w);
            half8 h = { p0[0], p0[1], p1[0], p1[1], p2[0], p2[1], p3[0], p3[1] };
            int ksx = ks ^ (m & 7);                       // XOR swizzle (write side)
            *(half8*)(&ldsA[buf][(size_t)((m << 3) + ksx) * 8]) = h;
        }
#pragma unroll
        for (int i = 0; i < 4; ++i) {
            int kb = kb0 + i * 16;
            half8 w;
#pragma unroll
            for (int j = 0; j < 8; ++j)
                w[j] = (_Float16)fmaf((float)bpre[i][j], spre, zpre);  // RTNE
            int ks = kb >> 3;
            *(half8*)(&ldsB[buf][(size_t)(ks * 128 + nB) * 8]) = w;
        }
    };

    // ---------------- prologue ----------------
    issue(0);
    writeLds(0);
    __syncthreads();

    int cur = 0;
    for (int t = 0; t < KTILES; ++t) {
        if (t + 1 < KTILES)
            issue(t + 1);                 // loads in flight during compute

        const _Float16* lA = ldsA[cur];
        const _Float16* lB = ldsB[cur];
#pragma unroll
        for (int half = 0; half < 2; ++half) {
            int ksb = half * 4 + (lane >> 4);
            half8 af[4], bfr[4];
#pragma unroll
            for (int mf = 0; mf < 4; ++mf) {
                int r = wr + mf * 16 + (lane & 15);
                int ksx = ksb ^ (r & 7);                  // XOR swizzle (read side)
                af[mf] = *(const half8*)(lA + (size_t)((r << 3) + ksx) * 8);
            }
#pragma unroll
            for (int nf = 0; nf < 4; ++nf) {
                int c = wc + nf * 16 + (lane & 15);
                bfr[nf] = *(const half8*)(lB + (size_t)(ksb * 128 + c) * 8);
            }
#pragma unroll
            for (int mf = 0; mf < 4; ++mf)
#pragma unroll
                for (int nf = 0; nf < 4; ++nf)
                    acc[mf][nf] = __builtin_amdgcn_mfma_f32_16x16x32_f16(
                        af[mf], bfr[nf], acc[mf][nf], 0, 0, 0);
        }

        if (t + 1 < KTILES) {
            writeLds(cur ^ 1);            // waits on its own loads only
            __syncthreads();              // one barrier per tile
            cur ^= 1;
        }
    }

    // ---------------- epilogue ----------------
    // C/D layout (dtype-independent): col = lane&15, row = (lane>>4)*4 + reg
    int rbase = m0 + wr + ((lane >> 4) << 2);
    int cbase = n0 + wc + (lane & 15);
#pragma unroll
    for (int mf = 0; mf < 4; ++mf)
#pragma unroll
        for (int nf = 0; nf < 4; ++nf)
#pragma unroll
            for (int rr = 0; rr < 4; ++rr) {
                int row = rbase + mf * 16 + rr;
                int col = cbase + nf * 16;
                out[(size_t)row * N_DIM + col] = acc[mf][nf][rr];
            }
}

extern "C" void kernel_launch(void* const* d_in, const int* in_sizes, int n_in,
                              void* d_out, int out_size, void* d_ws, size_t ws_size,
                              hipStream_t stream) {
    const float* A = (const float*)d_in[0];
    const int*   Q = (const int*)d_in[1];
    const float* S = (const float*)d_in[2];
    const float* Z = (const float*)d_in[3];
    float* O = (float*)d_out;

    l3z_gemm<<<dim3(NBLK), dim3(256), 0, stream>>>(A, Q, S, Z, O);
}